// Round 10
// baseline (177.006 us; speedup 1.0000x reference)
//
#include <hip/hip_runtime.h>
#include <hip/hip_bf16.h>

// BiaffineAttention on MI355X — round 10.
// r9 -> r10:
//  (a) S-fold: scores = t1h @ S @ t1d^T with S = MT^T @ W2 [512x512].
//      Eliminates the dep GEMM (8.6 -> 4.3 GF on the 8192-row mid stage).
//      Chain: rider1 (in g1mt) MTT = bt(w2hT, WbT); k_st: S = bt(MTT, W2T);
//      g2: dep2 = bt(t1d, S); g3: scores_b = bt(t1h_b, dep2_b) + bb.
//  (b) depth-3 prefetch (4 LDS slots): vmcnt(2*LPS) steady state — ~3 K-steps
//      of compute in flight covers L2/HBM stage latency (r9's 2-deep didn't).
//  (c) T5 s_setprio(1) around compute (counted-vmcnt gives wave role split).
// Keeps: T2 both-sides LDS XOR-swizzle (conflicts==0), wait-BEFORE-barrier
//        (r8 race fix), XCD-bijective swizzle, bias folds.

#define HIDDEN 1024
#define ARC 500
#define AP 512
#define ROWS 8192

typedef __attribute__((ext_vector_type(4))) float f32x4;
typedef __attribute__((ext_vector_type(8))) short short8;

static __device__ __forceinline__ ushort f2bf(float f) {
  union { float f; unsigned u; } v; v.f = f;
  unsigned r = v.u + 0x7fffu + ((v.u >> 16) & 1u);  // RNE
  return (ushort)(r >> 16);
}

// Fused weight-prep + hs fp32->bf16 conversion. Block ranges:
//  [0,4096)    W1 [1024x1024]: rows 0..499=w1h, 512..1011=w1d, else 0
//  [4096,5120) WbT[a][j] = Wb[j][a]
//  [5120,6144) w2hT[k][j] = w2h[j][k]; row 511 = b2h
//  [6144,7168) W2T[m][a] = W2[a][m]: w2d transposed; ROW 511 = b2d
//  [7168,7172) b1c: b1h | 0 | 1 | b1d | 0 | 1
//  [7172,9220) hs fp32 -> bf16 (grid-stride float4)
__global__ void k_prep_all(const float* __restrict__ w1h, const float* __restrict__ b1h,
                           const float* __restrict__ w1d, const float* __restrict__ b1d,
                           const float* __restrict__ w2h, const float* __restrict__ b2h,
                           const float* __restrict__ w2d, const float* __restrict__ b2d,
                           const float* __restrict__ Wb, const float4* __restrict__ hs,
                           ushort* __restrict__ W1, ushort* __restrict__ WbT,
                           ushort* __restrict__ w2hT, ushort* __restrict__ W2T,
                           float* __restrict__ b1c, ushort* __restrict__ hs_bf) {
  const int bid = blockIdx.x;
  const int tid = threadIdx.x;
  if (bid < 4096) {
    int idx = bid * 256 + tid;
    int n = idx >> 10, k = idx & 1023;
    float v = 0.f;
    if (n < ARC) v = w1h[(size_t)n * HIDDEN + k];
    else if (n >= AP && n < AP + ARC) v = w1d[(size_t)(n - AP) * HIDDEN + k];
    W1[idx] = f2bf(v);
  } else if (bid < 5120) {
    int idx = (bid - 4096) * 256 + tid;
    int a = idx >> 9, j = idx & 511;
    float v = (a < ARC && j < ARC) ? Wb[(size_t)j * ARC + a] : 0.f;
    WbT[idx] = f2bf(v);
  } else if (bid < 6144) {
    int idx = (bid - 5120) * 256 + tid;
    int k = idx >> 9, j = idx & 511;
    float v = 0.f;
    if (j < ARC) {
      if (k < ARC) v = w2h[(size_t)j * ARC + k];
      else if (k == 511) v = b2h[j];
    }
    w2hT[idx] = f2bf(v);
  } else if (bid < 7168) {
    int idx = (bid - 6144) * 256 + tid;
    int m = idx >> 9, a = idx & 511;  // W2T[m][a] = W2[a][m]
    float v = 0.f;
    if (a < ARC) {
      if (m < ARC) v = w2d[(size_t)a * ARC + m];
      else if (m == 511) v = b2d[a];
    }
    W2T[idx] = f2bf(v);
  } else if (bid < 7172) {
    int i = (bid - 7168) * 256 + tid;
    float v = 0.f;
    if (i < ARC) v = b1h[i];
    else if (i == 511 || i == 1023) v = 1.f;
    else if (i >= AP && i < AP + ARC) v = b1d[i - AP];
    b1c[i] = v;
  } else {
    const int n4 = ROWS * HIDDEN / 4;
    int i = (bid - 7172) * 256 + tid;
    for (; i < n4; i += 2048 * 256) {
      float4 v = hs[i];
      ushort4 o;
      o.x = f2bf(v.x); o.y = f2bf(v.y); o.z = f2bf(v.z); o.w = f2bf(v.w);
      *(ushort4*)(hs_bf + (size_t)i * 4) = o;
    }
  }
}

// ---- depth-3 counted-vmcnt bf16 GEMM body: C = A @ B^T ---------------------
// 128xBN tile, BK=32, 256 threads (4 waves 2x2), 16x16x32 bf16 MFMA.
// 4 LDS slots (BUFSZ ushorts each: A[4096] | B[BN*32]); prologue stages 3.
// Per K-step: vmcnt(2*LPS) [LPS at nt-2, 0 at nt-1]; s_barrier; stage(t+3);
//             setprio(1); compute(t); setprio(0).
// LDS swizzle (T2, both-sides): phys chunk p at row r holds global chunk
// p ^ ((r>>1)&3); pre-swizzled global source + swizzled ds_read (conflicts=0).
template <int BN>
__device__ __forceinline__ void gemm_body(
    const ushort* __restrict__ A, const ushort* __restrict__ B,
    const float* __restrict__ bias, int bias_mode,  // 0 none, 1 per-col, 2 scalar
    void* __restrict__ C, int out_bf16, int relu,
    int lda, int ldb, int ldc, int K, int tm, int tn, ushort* lds) {
  constexpr int WC = BN / 2;
  constexpr int NFR = WC / 16;
  constexpr int BUFSZ = 4096 + BN * 32;  // ushorts per slot

  const int t = threadIdx.x;
  const int w = t >> 6;
  const int l = t & 63;
  const int wr = w >> 1, wc = w & 1;

  f32x4 acc[4][NFR];
#pragma unroll
  for (int m = 0; m < 4; ++m)
#pragma unroll
    for (int n = 0; n < NFR; ++n) acc[m][n] = f32x4{0.f, 0.f, 0.f, 0.f};

  const int srow = w * 16 + (l >> 2);
  const int scol = (((l & 3) ^ ((l >> 3) & 3))) * 8;  // pre-swizzled global chunk
  const ushort* ag = A + (size_t)(tm + srow) * lda + scol;
  const ushort* bg = B + (size_t)(tn + srow) * ldb + scol;
  const int lofs = w * 512;  // wave-uniform LDS staging base (ushorts)

  const int fr = l & 15, fh = l >> 4;
  const int swz = (fr >> 1) & 3;                       // row-derived chunk XOR
  const int fAo = (wr * 64 + fr) * 32 + (fh ^ swz) * 8;
  const int fBo = (wc * WC + fr) * 32 + (fh ^ swz) * 8;

  auto stage = [&](int kt, ushort* buf) {
#pragma unroll
    for (int c = 0; c < 2; ++c)
      __builtin_amdgcn_global_load_lds(
          (const __attribute__((address_space(1))) void*)(ag + (size_t)c * 64 * lda + kt),
          (__attribute__((address_space(3))) void*)(buf + lofs + c * 2048), 16, 0, 0);
#pragma unroll
    for (int c = 0; c < BN / 64; ++c)
      __builtin_amdgcn_global_load_lds(
          (const __attribute__((address_space(1))) void*)(bg + (size_t)c * 64 * ldb + kt),
          (__attribute__((address_space(3))) void*)(buf + 4096 + lofs + c * 2048), 16, 0, 0);
  };
  auto compute = [&](const ushort* buf) {
    short8 af[4], bf[NFR];
#pragma unroll
    for (int m = 0; m < 4; ++m) af[m] = *(const short8*)(buf + fAo + m * 16 * 32);
#pragma unroll
    for (int n = 0; n < NFR; ++n) bf[n] = *(const short8*)(buf + 4096 + fBo + n * 16 * 32);
#pragma unroll
    for (int m = 0; m < 4; ++m)
#pragma unroll
      for (int n = 0; n < NFR; ++n)
        acc[m][n] = __builtin_amdgcn_mfma_f32_16x16x32_bf16(af[m], bf[n], acc[m][n], 0, 0, 0);
  };

  const int nt = K >> 5;  // >= 16 for all our GEMMs
  stage(0, lds);
  stage(32, lds + BUFSZ);
  stage(64, lds + 2 * BUFSZ);
  int cs = 0, ps = 3;
  for (int ti = 0; ti < nt; ++ti) {
    // WAIT FIRST (per-wave), counted: keep up to 2 later stages in flight.
    if (ti < nt - 2) {
      if constexpr (BN == 128) asm volatile("s_waitcnt vmcnt(8)" ::: "memory");
      else                     asm volatile("s_waitcnt vmcnt(6)" ::: "memory");
    } else if (ti == nt - 2) {
      if constexpr (BN == 128) asm volatile("s_waitcnt vmcnt(4)" ::: "memory");
      else                     asm volatile("s_waitcnt vmcnt(3)" ::: "memory");
    } else {
      asm volatile("s_waitcnt vmcnt(0)" ::: "memory");
    }
    // THEN BARRIER: all waves certified stage(ti) -> tile ready; slot
    // (ti+3)&3 was read by compute(ti-1) which finished before this barrier.
    __builtin_amdgcn_s_barrier();
    __builtin_amdgcn_sched_barrier(0);
    if (ti + 3 < nt) stage((ti + 3) << 5, lds + ps * BUFSZ);
    __builtin_amdgcn_s_setprio(1);
    compute(lds + cs * BUFSZ);
    __builtin_amdgcn_s_setprio(0);
    cs = (cs + 1) & 3;
    ps = (ps + 1) & 3;
  }

  // C/D layout: col = lane&15, row = (lane>>4)*4 + j  [m89-verified]
  const int cr = fh * 4;
  const float bscal = (bias_mode == 2) ? bias[0] : 0.f;
#pragma unroll
  for (int m = 0; m < 4; ++m) {
#pragma unroll
    for (int n = 0; n < NFR; ++n) {
      const int col = tn + wc * WC + n * 16 + fr;
      const float bv = (bias_mode == 1) ? bias[col] : bscal;
#pragma unroll
      for (int j = 0; j < 4; ++j) {
        const int row = tm + wr * 64 + m * 16 + cr + j;
        float v = acc[m][n][j] + bv;
        if (relu) v = fmaxf(v, 0.f);
        if (out_bf16)
          ((ushort*)C)[(size_t)row * ldc + col] = f2bf(v);
        else
          ((float*)C)[(size_t)row * ldc + col] = v;
      }
    }
  }
}

// GEMM1 (t1 = relu(hs@W1^T + b1c), 8192x1024 K=1024) + rider1 MTT.
// grid (8, 66): by<64 -> GEMM1 tile; by>=64 -> MTT = bt(w2hT, WbT) [512x512].
__global__ __launch_bounds__(256)
void k_g1mt(const ushort* __restrict__ hs_bf, const ushort* __restrict__ W1,
            const float* __restrict__ b1c, ushort* __restrict__ t1,
            const ushort* __restrict__ w2hT, const ushort* __restrict__ WbT,
            ushort* __restrict__ MTT) {
  __shared__ ushort lds[4 * 8192];  // 64 KB: 4 slots x (A 8KB | B 8KB)
  const int flat = blockIdx.y * 8 + blockIdx.x;  // 528 blocks, %8==0
  const int f2 = (flat & 7) * 66 + (flat >> 3);  // XCD-bijective swizzle
  const int by = f2 >> 3, bx = f2 & 7;
  if (by < 64) {
    gemm_body<128>(hs_bf, W1, b1c, 1, t1, 1, 1,
                   HIDDEN, HIDDEN, 1024, HIDDEN, by * 128, bx * 128, lds);
  } else {
    const int idx = (by - 64) * 8 + bx;  // [0,16)
    // MTT[k][a] = sum_j w2hT[k][j] * WbT[a][j]  (= MT[a][k])
    gemm_body<128>(w2hT, WbT, nullptr, 0, MTT, 1, 0,
                   AP, AP, AP, AP, (idx >> 2) * 128, (idx & 3) * 128, lds);
  }
}

// Generic batched GEMM: z-strided A/B/C (element strides), runtime flags.
template <int BN>
__global__ __launch_bounds__(256)
void k_gemm_rt(const ushort* __restrict__ A, const ushort* __restrict__ B,
               const float* __restrict__ bias, int bias_mode,
               void* __restrict__ C, int out_bf16, int relu,
               int lda, int ldb, int ldc, int K,
               long aBS, long bBS, long cBS) {
  __shared__ ushort lds[4 * (4096 + BN * 32)];
  const int gx = gridDim.x, gy = gridDim.y;
  const int gxy = gx * gy;
  const int nwg = gxy * gridDim.z;
  const int flat = (blockIdx.z * gy + blockIdx.y) * gx + blockIdx.x;
  const int q = nwg >> 3;
  const int f2 = (flat & 7) * q + (flat >> 3);  // bijective: nwg % 8 == 0
  const int bz = f2 / gxy;
  const int rm = f2 - bz * gxy;
  const int by = rm / gx;
  const int bx = rm - by * gx;

  const ushort* Az = A + (size_t)aBS * bz;
  const ushort* Bz = B + (size_t)bBS * bz;
  void* Cz = out_bf16 ? (void*)((ushort*)C + (size_t)cBS * bz)
                      : (void*)((float*)C + (size_t)cBS * bz);
  gemm_body<BN>(Az, Bz, bias, bias_mode, Cz, out_bf16, relu,
                lda, ldb, ldc, K, by * 128, bx * BN, lds);
}

extern "C" void kernel_launch(void* const* d_in, const int* in_sizes, int n_in,
                              void* d_out, int out_size, void* d_ws, size_t ws_size,
                              hipStream_t stream) {
  const float* hs  = (const float*)d_in[0];
  const float* w1h = (const float*)d_in[1];
  const float* b1h = (const float*)d_in[2];
  const float* w2h = (const float*)d_in[3];
  const float* b2h = (const float*)d_in[4];
  const float* w1d = (const float*)d_in[5];
  const float* b1d = (const float*)d_in[6];
  const float* w2d = (const float*)d_in[7];
  const float* b2d = (const float*)d_in[8];
  const float* Wb  = (const float*)d_in[9];
  const float* bb  = (const float*)d_in[10];

  char* ws = (char*)d_ws;
  ushort* hs_bf = (ushort*)(ws + 0);          // 16 MB
  ushort* W1    = (ushort*)(ws + 16777216);   // 2 MB
  ushort* WbT   = (ushort*)(ws + 18874368);   // 512 KB
  ushort* w2hT  = (ushort*)(ws + 19398656);   // 512 KB
  ushort* MTT   = (ushort*)(ws + 19922944);   // 512 KB
  ushort* W2T   = (ushort*)(ws + 20447232);   // 512 KB
  ushort* t1    = (ushort*)(ws + 20971520);   // 16 MB
  ushort* dep2  = (ushort*)(ws + 37748736);   // 8 MB
  ushort* S     = (ushort*)(ws + 46137344);   // 512 KB
  float*  b1c   = (float*)(ws + 54525952);    // 4 KB
  float*  out   = (float*)d_out;

  k_prep_all<<<9220, 256, 0, stream>>>(w1h, b1h, w1d, b1d, w2h, b2h, w2d, b2d,
                                       Wb, (const float4*)hs,
                                       W1, WbT, w2hT, W2T, b1c, hs_bf);

  // GEMM1 + rider1 (MTT) in one dispatch
  k_g1mt<<<dim3(8, 66), 256, 0, stream>>>(hs_bf, W1, b1c, t1, w2hT, WbT, MTT);

  // rider2: S[k][m] = sum_a MTT[k][a] * W2T[m][a]  [512x512], K=512
  k_gemm_rt<128><<<dim3(4, 4, 1), 256, 0, stream>>>(
      MTT, W2T, nullptr, 0, S, 1, 0, AP, AP, AP, AP, 0, 0, 0);

  // GEMM2': dep2[j][k] = sum_m t1d[j][m] * S[k][m]  [8192x512], K=512
  k_gemm_rt<128><<<dim3(4, 64, 1), 256, 0, stream>>>(
      t1 + AP, S, nullptr, 0, dep2, 1, 0, 1024, AP, AP, AP, 0, 0, 0);

  // GEMM3: scores_b[i][j] = sum_k t1h_b[i][k] * dep2_b[j][k] + bb -> f32 out
  k_gemm_rt<64><<<dim3(8, 4, 16), 256, 0, stream>>>(
      t1, dep2, bb, 2, out, 0, 0, 1024, AP, 512, AP,
      /*aBS=*/(long)512 * 1024, /*bBS=*/(long)512 * AP, /*cBS=*/(long)512 * 512);
}

// Round 13
// 169.677 us; speedup vs baseline: 1.0432x; 1.0432x over previous
//
#include <hip/hip_runtime.h>
#include <hip/hip_bf16.h>

// BiaffineAttention on MI355X — round 11 design (3rd submit; r11+r12 benches
// were infra timeouts, kernel has never run).
// r10 post-mortem: S-fold regressed (longer serial chain, tiny rider dispatch);
// depth-3 (64KB LDS) cut occupancy 3->2 blocks/CU. Root cause across r4-r10:
// grids of 512 blocks = 2 blocks/CU = 2 waves/SIMD (Occupancy 10.5%) — all
// GEMMs latency-bound with no TLP.
// r11: revert to r9 dataflow (4 dispatches, z=2 GEMM2); tiles BMxBN = 128x64
// (GEMM1/2) and 64x64 (GEMM3) -> 1024 blocks per GEMM = 4 blocks/CU =
// 4 waves/SIMD. 3 LDS slots (36/24 KB -> 4+ blocks/CU fits). Depth-2
// counted-vmcnt schedule as r9 (wait LPS -> barrier -> stage(t+2) -> compute).
// Keeps: T2 both-sides LDS XOR-swizzle (conflicts==0), XCD-bijective swizzle,
// algebraic bias folds (absmax 0.03125 verified r9).

#define HIDDEN 1024
#define ARC 500
#define AP 512
#define ROWS 8192

typedef __attribute__((ext_vector_type(4))) float f32x4;
typedef __attribute__((ext_vector_type(8))) short short8;

static __device__ __forceinline__ ushort f2bf(float f) {
  union { float f; unsigned u; } v; v.f = f;
  unsigned r = v.u + 0x7fffu + ((v.u >> 16) & 1u);  // RNE
  return (ushort)(r >> 16);
}

// Fused weight-prep + hs fp32->bf16 conversion. Block ranges:
//  [0,4096)    W1 [1024x1024]: rows 0..499=w1h, 512..1011=w1d, else 0
//  [4096,5120) WbT[a][j] = Wb[j][a]
//  [5120,6144) w2hT[k][j] = w2h[j][k]; row 511 = b2h
//  [6144,7168) W2 = w2d padded; col 511 = b2d
//  [7168,7172) b1c: b1h | 0 | 1 | b1d | 0 | 1
//  [7172,9220) hs fp32 -> bf16 (grid-stride float4)
__global__ void k_prep_all(const float* __restrict__ w1h, const float* __restrict__ b1h,
                           const float* __restrict__ w1d, const float* __restrict__ b1d,
                           const float* __restrict__ w2h, const float* __restrict__ b2h,
                           const float* __restrict__ w2d, const float* __restrict__ b2d,
                           const float* __restrict__ Wb, const float4* __restrict__ hs,
                           ushort* __restrict__ W1, ushort* __restrict__ WbT,
                           ushort* __restrict__ w2hT, ushort* __restrict__ W2,
                           float* __restrict__ b1c, ushort* __restrict__ hs_bf) {
  const int bid = blockIdx.x;
  const int tid = threadIdx.x;
  if (bid < 4096) {
    int idx = bid * 256 + tid;
    int n = idx >> 10, k = idx & 1023;
    float v = 0.f;
    if (n < ARC) v = w1h[(size_t)n * HIDDEN + k];
    else if (n >= AP && n < AP + ARC) v = w1d[(size_t)(n - AP) * HIDDEN + k];
    W1[idx] = f2bf(v);
  } else if (bid < 5120) {
    int idx = (bid - 4096) * 256 + tid;
    int a = idx >> 9, j = idx & 511;
    float v = (a < ARC && j < ARC) ? Wb[(size_t)j * ARC + a] : 0.f;
    WbT[idx] = f2bf(v);
  } else if (bid < 6144) {
    int idx = (bid - 5120) * 256 + tid;
    int k = idx >> 9, j = idx & 511;
    float v = 0.f;
    if (j < ARC) {
      if (k < ARC) v = w2h[(size_t)j * ARC + k];
      else if (k == 511) v = b2h[j];
    }
    w2hT[idx] = f2bf(v);
  } else if (bid < 7168) {
    int idx = (bid - 6144) * 256 + tid;
    int n = idx >> 9, k = idx & 511;
    float v = 0.f;
    if (n < ARC) {
      if (k < ARC) v = w2d[(size_t)n * ARC + k];
      else if (k == 511) v = b2d[n];
    }
    W2[idx] = f2bf(v);
  } else if (bid < 7172) {
    int i = (bid - 7168) * 256 + tid;
    float v = 0.f;
    if (i < ARC) v = b1h[i];
    else if (i == 511 || i == 1023) v = 1.f;
    else if (i >= AP && i < AP + ARC) v = b1d[i - AP];
    b1c[i] = v;
  } else {
    const int n4 = ROWS * HIDDEN / 4;
    int i = (bid - 7172) * 256 + tid;
    for (; i < n4; i += 2048 * 256) {
      float4 v = hs[i];
      ushort4 o;
      o.x = f2bf(v.x); o.y = f2bf(v.y); o.z = f2bf(v.z); o.w = f2bf(v.w);
      *(ushort4*)(hs_bf + (size_t)i * 4) = o;
    }
  }
}

// ---- depth-2 counted-vmcnt bf16 GEMM body: C = A @ B^T ---------------------
// BMxBN tile, BK=32, 256 threads (4 waves 2x2; wave tile BM/2 x BN/2).
// 3 LDS slots, each (BM+BN)*32 ushorts: A[BM*32] | B[BN*32].
// Schedule (r8-verified race-free): vmcnt(LPS) [0 last] -> s_barrier ->
// stage(t+2) -> compute(t).
// T2 swizzle: phys 16B-chunk p at row r holds global chunk p^((r>>1)&3);
// pre-swizzled global source + swizzled ds_read (r6: conflicts 0).
template <int BM, int BN>
__device__ __forceinline__ void gemm_body(
    const ushort* __restrict__ A, const ushort* __restrict__ B,
    const float* __restrict__ bias, int bias_mode,  // 0 none, 1 per-col, 2 scalar
    void* __restrict__ C, int out_bf16, int relu,
    int lda, int ldb, int ldc, int K, int tm, int tn, ushort* lds) {
  constexpr int WR = BM / 2, WCC = BN / 2;   // wave tile
  constexpr int MFR = WR / 16, NFR = WCC / 16;
  constexpr int CA = BM / 64, CB = BN / 64;  // stage calls per operand
  constexpr int LPS = CA + CB;               // loads per stage (per thread)
  constexpr int BUFSZ = (BM + BN) * 32;      // ushorts per slot

  const int t = threadIdx.x;
  const int w = t >> 6;
  const int l = t & 63;
  const int wr = w >> 1, wc = w & 1;

  f32x4 acc[MFR][NFR];
#pragma unroll
  for (int m = 0; m < MFR; ++m)
#pragma unroll
    for (int n = 0; n < NFR; ++n) acc[m][n] = f32x4{0.f, 0.f, 0.f, 0.f};

  const int srow = w * 16 + (l >> 2);
  const int scol = (((l & 3) ^ ((l >> 3) & 3))) * 8;  // pre-swizzled global chunk
  const ushort* ag = A + (size_t)(tm + srow) * lda + scol;
  const ushort* bg = B + (size_t)(tn + srow) * ldb + scol;
  const int lofs = w * 512;  // wave-uniform LDS staging base (ushorts)

  const int fr = l & 15, fh = l >> 4;
  const int swz = (fr >> 1) & 3;                       // row-derived chunk XOR
  const int fAo = (wr * WR + fr) * 32 + (fh ^ swz) * 8;
  const int fBo = (wc * WCC + fr) * 32 + (fh ^ swz) * 8;

  auto stage = [&](int kt, ushort* buf) {
#pragma unroll
    for (int c = 0; c < CA; ++c)
      __builtin_amdgcn_global_load_lds(
          (const __attribute__((address_space(1))) void*)(ag + (size_t)c * 64 * lda + kt),
          (__attribute__((address_space(3))) void*)(buf + lofs + c * 2048), 16, 0, 0);
#pragma unroll
    for (int c = 0; c < CB; ++c)
      __builtin_amdgcn_global_load_lds(
          (const __attribute__((address_space(1))) void*)(bg + (size_t)c * 64 * ldb + kt),
          (__attribute__((address_space(3))) void*)(buf + BM * 32 + lofs + c * 2048), 16, 0, 0);
  };
  auto compute = [&](const ushort* buf) {
    short8 af[MFR], bf[NFR];
#pragma unroll
    for (int m = 0; m < MFR; ++m) af[m] = *(const short8*)(buf + fAo + m * 16 * 32);
#pragma unroll
    for (int n = 0; n < NFR; ++n) bf[n] = *(const short8*)(buf + BM * 32 + fBo + n * 16 * 32);
#pragma unroll
    for (int m = 0; m < MFR; ++m)
#pragma unroll
      for (int n = 0; n < NFR; ++n)
        acc[m][n] = __builtin_amdgcn_mfma_f32_16x16x32_bf16(af[m], bf[n], acc[m][n], 0, 0, 0);
  };

  const int nt = K >> 5;  // >= 16 for all our GEMMs
  stage(0, lds);
  stage(32, lds + BUFSZ);
  int cs = 0, ps = 2;
  for (int ti = 0; ti < nt; ++ti) {
    // WAIT FIRST (per-wave): my stage(ti) loads landed; leave stage(ti+1)'s
    // LPS loads in flight. THEN barrier certifies all waves.
    if (ti + 1 < nt) {
      if constexpr (LPS == 2)      asm volatile("s_waitcnt vmcnt(2)" ::: "memory");
      else if constexpr (LPS == 3) asm volatile("s_waitcnt vmcnt(3)" ::: "memory");
      else                         asm volatile("s_waitcnt vmcnt(4)" ::: "memory");
    } else {
      asm volatile("s_waitcnt vmcnt(0)" ::: "memory");
    }
    __builtin_amdgcn_s_barrier();
    __builtin_amdgcn_sched_barrier(0);
    if (ti + 2 < nt) stage((ti + 2) << 5, lds + ps * BUFSZ);
    compute(lds + cs * BUFSZ);
    cs = (cs == 2) ? 0 : cs + 1;
    ps = (ps == 2) ? 0 : ps + 1;
  }

  // C/D layout: col = lane&15, row = (lane>>4)*4 + j  [m89-verified]
  const int cr = fh * 4;
  const float bscal = (bias_mode == 2) ? bias[0] : 0.f;
#pragma unroll
  for (int m = 0; m < MFR; ++m) {
#pragma unroll
    for (int n = 0; n < NFR; ++n) {
      const int col = tn + wc * WCC + n * 16 + fr;
      const float bv = (bias_mode == 1) ? bias[col] : bscal;
#pragma unroll
      for (int j = 0; j < 4; ++j) {
        const int row = tm + wr * WR + m * 16 + cr + j;
        float v = acc[m][n][j] + bv;
        if (relu) v = fmaxf(v, 0.f);
        if (out_bf16)
          ((ushort*)C)[(size_t)row * ldc + col] = f2bf(v);
        else
          ((float*)C)[(size_t)row * ldc + col] = v;
      }
    }
  }
}

// GEMM1 (t1 = relu(hs@W1^T + b1c), 8192x1024 K=1024, 128x64 tiles -> 1024
// blocks) + MT rider (MT = bt(WbT, w2hT) [512x512] K=512, 32 blocks).
// grid (8, 132) = 1056 blocks (%8==0).
__global__ __launch_bounds__(256)
void k_g1mt(const ushort* __restrict__ hs_bf, const ushort* __restrict__ W1,
            const float* __restrict__ b1c, ushort* __restrict__ t1,
            const ushort* __restrict__ WbT, const ushort* __restrict__ w2hT,
            ushort* __restrict__ MTb) {
  __shared__ ushort lds[3 * (128 + 64) * 32];  // 36 KB -> 4 blocks/CU
  const int flat = blockIdx.y * 8 + blockIdx.x;
  const int f2 = (flat & 7) * 132 + (flat >> 3);  // XCD-bijective swizzle
  if (f2 < 1024) {
    const int by = f2 >> 4, bx = f2 & 15;  // 64 x 16 tiles
    gemm_body<128, 64>(hs_bf, W1, b1c, 1, t1, 1, 1,
                       HIDDEN, HIDDEN, 1024, HIDDEN, by * 128, bx * 64, lds);
  } else {
    const int idx = f2 - 1024;  // [0,32): 4 x 8 tiles
    gemm_body<128, 64>(WbT, w2hT, nullptr, 0, MTb, 1, 0,
                       AP, AP, AP, AP, (idx >> 3) * 128, (idx & 7) * 64, lds);
  }
}

// Generic batched GEMM: z-strided A/B/C (element strides), runtime flags.
template <int BM, int BN>
__global__ __launch_bounds__(256)
void k_gemm_rt(const ushort* __restrict__ A, const ushort* __restrict__ B,
               const float* __restrict__ bias, int bias_mode,
               void* __restrict__ C, int out_bf16, int relu,
               int lda, int ldb, int ldc, int K,
               long aBS, long bBS, long cBS) {
  __shared__ ushort lds[3 * (BM + BN) * 32];
  const int gx = gridDim.x, gy = gridDim.y;
  const int gxy = gx * gy;
  const int nwg = gxy * gridDim.z;
  const int flat = (blockIdx.z * gy + blockIdx.y) * gx + blockIdx.x;
  const int q = nwg >> 3;
  const int f2 = (flat & 7) * q + (flat >> 3);  // bijective: nwg % 8 == 0
  const int bz = f2 / gxy;
  const int rm = f2 - bz * gxy;
  const int by = rm / gx;
  const int bx = rm - by * gx;

  const ushort* Az = A + (size_t)aBS * bz;
  const ushort* Bz = B + (size_t)bBS * bz;
  void* Cz = out_bf16 ? (void*)((ushort*)C + (size_t)cBS * bz)
                      : (void*)((float*)C + (size_t)cBS * bz);
  gemm_body<BM, BN>(Az, Bz, bias, bias_mode, Cz, out_bf16, relu,
                    lda, ldb, ldc, K, by * BM, bx * BN, lds);
}

extern "C" void kernel_launch(void* const* d_in, const int* in_sizes, int n_in,
                              void* d_out, int out_size, void* d_ws, size_t ws_size,
                              hipStream_t stream) {
  const float* hs  = (const float*)d_in[0];
  const float* w1h = (const float*)d_in[1];
  const float* b1h = (const float*)d_in[2];
  const float* w2h = (const float*)d_in[3];
  const float* b2h = (const float*)d_in[4];
  const float* w1d = (const float*)d_in[5];
  const float* b1d = (const float*)d_in[6];
  const float* w2d = (const float*)d_in[7];
  const float* b2d = (const float*)d_in[8];
  const float* Wb  = (const float*)d_in[9];
  const float* bb  = (const float*)d_in[10];

  char* ws = (char*)d_ws;
  ushort* hs_bf = (ushort*)(ws + 0);          // 16 MB
  ushort* W1    = (ushort*)(ws + 16777216);   // 2 MB
  ushort* WbT   = (ushort*)(ws + 18874368);   // 512 KB
  ushort* w2hT  = (ushort*)(ws + 19398656);   // 512 KB
  ushort* MT    = (ushort*)(ws + 19922944);   // 512 KB
  ushort* W2    = (ushort*)(ws + 20447232);   // 512 KB (= MT + 512*512 elems!)
  ushort* t1    = (ushort*)(ws + 20971520);   // 16 MB
  ushort* hw    = (ushort*)(ws + 37748736);   // 16 MB (headW 8MB | dep 8MB)
  float*  b1c   = (float*)(ws + 54525952);    // 4 KB
  float*  out   = (float*)d_out;

  k_prep_all<<<9220, 256, 0, stream>>>(w1h, b1h, w1d, b1d, w2h, b2h, w2d, b2d,
                                       Wb, (const float4*)hs,
                                       W1, WbT, w2hT, W2, b1c, hs_bf);

  // GEMM1 + MT rider: 1056 blocks
  k_g1mt<<<dim3(8, 132), 256, 0, stream>>>(hs_bf, W1, b1c, t1, WbT, w2hT, MT);

  // GEMM2: z=0 headW = t1[:,:512] @ MT^T ; z=1 dep = t1[:,512:] @ W2^T
  // 128x64 tiles: (8, 64, 2) = 1024 blocks.
  k_gemm_rt<128, 64><<<dim3(8, 64, 2), 256, 0, stream>>>(
      t1, MT, nullptr, 0, hw, 1, 0, 1024, AP, AP, AP,
      /*aBS=*/AP, /*bBS=*/(long)AP * AP, /*cBS=*/(long)ROWS * AP);

  // GEMM3: scores_b = headW_b @ dep_b^T + bb -> f32 out.
  // 64x64 tiles: (8, 8, 16) = 1024 blocks.
  k_gemm_rt<64, 64><<<dim3(8, 8, 16), 256, 0, stream>>>(
      hw, hw + (size_t)ROWS * AP, bb, 2, out, 0, 0, AP, AP, 512, AP,
      /*aBS=*/(long)512 * AP, /*bBS=*/(long)512 * AP, /*cBS=*/(long)512 * 512);
}

// Round 15
// 163.777 us; speedup vs baseline: 1.0808x; 1.0360x over previous
//
#include <hip/hip_runtime.h>
#include <hip/hip_bf16.h>

// BiaffineAttention on MI355X — round 14 (resubmit; r14 bench was an infra
// failure, kernel never ran).
// r13 post-mortem: occupancy-doubling null (r13 169.7 vs r9 163.3) — second
// falsified structural theory (after bank conflicts). Larger tiles won.
// r14: (1) revert GEMM tiles to r9's best config (g1mt 128x128, GEMM2 128x128
// z=2, GEMM3 128x64); (2) coalesced 64x64 LDS-tile transposes in prep (old
// path: stride-2000B scattered reads); (3) T5 s_setprio(1) around compute —
// isolated probe on the counted-vmcnt structure (m218b regime).
// Keeps: depth-2 counted-vmcnt (wait-before-barrier, r8 race fix), T2
// both-sides LDS XOR-swizzle (conflicts==0), XCD-bijective swizzle, bias folds.

#define HIDDEN 1024
#define ARC 500
#define AP 512
#define ROWS 8192

typedef __attribute__((ext_vector_type(4))) float f32x4;
typedef __attribute__((ext_vector_type(8))) short short8;

static __device__ __forceinline__ ushort f2bf(float f) {
  union { float f; unsigned u; } v; v.f = f;
  unsigned r = v.u + 0x7fffu + ((v.u >> 16) & 1u);  // RNE
  return (ushort)(r >> 16);
}

// Fused weight-prep + hs fp32->bf16 conversion. Block ranges:
//  [0,4096)    W1 [1024x1024]: rows 0..499=w1h, 512..1011=w1d, else 0
//  [4096,5120) W2 = w2d padded; col 511 = b2d   (direct, coalesced)
//  [5120,5184) WbT[a][j] = Wb[j][a]      (64x64 LDS-tile transpose)
//  [5184,5248) w2hT[k][j] = w2h[j][k]; row 511 = b2h  (LDS-tile transpose)
//  [5248,5252) b1c: b1h | 0 | 1 | b1d | 0 | 1
//  [5252,7300) hs fp32 -> bf16 (grid-stride float4)
__global__ void k_prep_all(const float* __restrict__ w1h, const float* __restrict__ b1h,
                           const float* __restrict__ w1d, const float* __restrict__ b1d,
                           const float* __restrict__ w2h, const float* __restrict__ b2h,
                           const float* __restrict__ w2d, const float* __restrict__ b2d,
                           const float* __restrict__ Wb, const float4* __restrict__ hs,
                           ushort* __restrict__ W1, ushort* __restrict__ WbT,
                           ushort* __restrict__ w2hT, ushort* __restrict__ W2,
                           float* __restrict__ b1c, ushort* __restrict__ hs_bf) {
  __shared__ float tlds[64 * 65];  // transpose tile, +1 pad (2-way free)
  const int bid = blockIdx.x;
  const int tid = threadIdx.x;
  if (bid < 4096) {
    int idx = bid * 256 + tid;
    int n = idx >> 10, k = idx & 1023;
    float v = 0.f;
    if (n < ARC) v = w1h[(size_t)n * HIDDEN + k];
    else if (n >= AP && n < AP + ARC) v = w1d[(size_t)(n - AP) * HIDDEN + k];
    W1[idx] = f2bf(v);
  } else if (bid < 5120) {
    int idx = (bid - 4096) * 256 + tid;
    int n = idx >> 9, k = idx & 511;
    float v = 0.f;
    if (n < ARC) {
      if (k < ARC) v = w2d[(size_t)n * ARC + k];
      else if (k == 511) v = b2d[n];
    }
    W2[idx] = f2bf(v);
  } else if (bid < 5184) {
    // WbT[a][j] = Wb[j][a], tiles 64x64: read rows of Wb (coalesced),
    // transpose via LDS, write rows of WbT (coalesced).
    const int tile = bid - 5120;            // 0..63
    const int ta = tile >> 3, tj = tile & 7;
#pragma unroll
    for (int i = 0; i < 16; ++i) {
      int e = i * 256 + tid;
      int jl = e >> 6, al = e & 63;
      int j = tj * 64 + jl, a = ta * 64 + al;
      tlds[jl * 65 + al] = (j < ARC && a < ARC) ? Wb[(size_t)j * ARC + a] : 0.f;
    }
    __syncthreads();
#pragma unroll
    for (int i = 0; i < 16; ++i) {
      int e = i * 256 + tid;
      int al = e >> 6, jl = e & 63;
      WbT[(size_t)(ta * 64 + al) * AP + tj * 64 + jl] = f2bf(tlds[jl * 65 + al]);
    }
  } else if (bid < 5248) {
    // w2hT[k][j] = w2h[j][k]; row 511 = b2h[j].
    const int tile = bid - 5184;
    const int tk = tile >> 3, tj = tile & 7;
#pragma unroll
    for (int i = 0; i < 16; ++i) {
      int e = i * 256 + tid;
      int jl = e >> 6, kl = e & 63;
      int j = tj * 64 + jl, k = tk * 64 + kl;
      tlds[jl * 65 + kl] = (j < ARC && k < ARC) ? w2h[(size_t)j * ARC + k] : 0.f;
    }
    __syncthreads();
#pragma unroll
    for (int i = 0; i < 16; ++i) {
      int e = i * 256 + tid;
      int kl = e >> 6, jl = e & 63;
      int k = tk * 64 + kl, j = tj * 64 + jl;
      float v = tlds[jl * 65 + kl];
      if (k == 511) v = (j < ARC) ? b2h[j] : 0.f;
      w2hT[(size_t)k * AP + j] = f2bf(v);
    }
  } else if (bid < 5252) {
    int i = (bid - 5248) * 256 + tid;
    float v = 0.f;
    if (i < ARC) v = b1h[i];
    else if (i == 511 || i == 1023) v = 1.f;
    else if (i >= AP && i < AP + ARC) v = b1d[i - AP];
    b1c[i] = v;
  } else {
    const int n4 = ROWS * HIDDEN / 4;
    int i = (bid - 5252) * 256 + tid;
    for (; i < n4; i += 2048 * 256) {
      float4 v = hs[i];
      ushort4 o;
      o.x = f2bf(v.x); o.y = f2bf(v.y); o.z = f2bf(v.z); o.w = f2bf(v.w);
      *(ushort4*)(hs_bf + (size_t)i * 4) = o;
    }
  }
}

// ---- depth-2 counted-vmcnt bf16 GEMM body: C = A @ B^T ---------------------
// BMxBN tile, BK=32, 256 threads (4 waves 2x2; wave tile BM/2 x BN/2).
// 3 LDS slots, each (BM+BN)*32 ushorts: A[BM*32] | B[BN*32].
// Schedule (r8-verified race-free): vmcnt(LPS) [0 last] -> s_barrier ->
// stage(t+2) -> setprio(1) compute(t) setprio(0).
// T2 swizzle: phys 16B-chunk p at row r holds global chunk p^((r>>1)&3);
// pre-swizzled global source + swizzled ds_read (r6: conflicts 0).
template <int BM, int BN>
__device__ __forceinline__ void gemm_body(
    const ushort* __restrict__ A, const ushort* __restrict__ B,
    const float* __restrict__ bias, int bias_mode,  // 0 none, 1 per-col, 2 scalar
    void* __restrict__ C, int out_bf16, int relu,
    int lda, int ldb, int ldc, int K, int tm, int tn, ushort* lds) {
  constexpr int WR = BM / 2, WCC = BN / 2;   // wave tile
  constexpr int MFR = WR / 16, NFR = WCC / 16;
  constexpr int CA = BM / 64, CB = BN / 64;  // stage calls per operand
  constexpr int LPS = CA + CB;               // loads per stage (per thread)
  constexpr int BUFSZ = (BM + BN) * 32;      // ushorts per slot

  const int t = threadIdx.x;
  const int w = t >> 6;
  const int l = t & 63;
  const int wr = w >> 1, wc = w & 1;

  f32x4 acc[MFR][NFR];
#pragma unroll
  for (int m = 0; m < MFR; ++m)
#pragma unroll
    for (int n = 0; n < NFR; ++n) acc[m][n] = f32x4{0.f, 0.f, 0.f, 0.f};

  const int srow = w * 16 + (l >> 2);
  const int scol = (((l & 3) ^ ((l >> 3) & 3))) * 8;  // pre-swizzled global chunk
  const ushort* ag = A + (size_t)(tm + srow) * lda + scol;
  const ushort* bg = B + (size_t)(tn + srow) * ldb + scol;
  const int lofs = w * 512;  // wave-uniform LDS staging base (ushorts)

  const int fr = l & 15, fh = l >> 4;
  const int swz = (fr >> 1) & 3;                       // row-derived chunk XOR
  const int fAo = (wr * WR + fr) * 32 + (fh ^ swz) * 8;
  const int fBo = (wc * WCC + fr) * 32 + (fh ^ swz) * 8;

  auto stage = [&](int kt, ushort* buf) {
#pragma unroll
    for (int c = 0; c < CA; ++c)
      __builtin_amdgcn_global_load_lds(
          (const __attribute__((address_space(1))) void*)(ag + (size_t)c * 64 * lda + kt),
          (__attribute__((address_space(3))) void*)(buf + lofs + c * 2048), 16, 0, 0);
#pragma unroll
    for (int c = 0; c < CB; ++c)
      __builtin_amdgcn_global_load_lds(
          (const __attribute__((address_space(1))) void*)(bg + (size_t)c * 64 * ldb + kt),
          (__attribute__((address_space(3))) void*)(buf + BM * 32 + lofs + c * 2048), 16, 0, 0);
  };
  auto compute = [&](const ushort* buf) {
    short8 af[MFR], bf[NFR];
#pragma unroll
    for (int m = 0; m < MFR; ++m) af[m] = *(const short8*)(buf + fAo + m * 16 * 32);
#pragma unroll
    for (int n = 0; n < NFR; ++n) bf[n] = *(const short8*)(buf + BM * 32 + fBo + n * 16 * 32);
#pragma unroll
    for (int m = 0; m < MFR; ++m)
#pragma unroll
      for (int n = 0; n < NFR; ++n)
        acc[m][n] = __builtin_amdgcn_mfma_f32_16x16x32_bf16(af[m], bf[n], acc[m][n], 0, 0, 0);
  };

  const int nt = K >> 5;  // >= 16 for all our GEMMs
  stage(0, lds);
  stage(32, lds + BUFSZ);
  int cs = 0, ps = 2;
  for (int ti = 0; ti < nt; ++ti) {
    // WAIT FIRST (per-wave): my stage(ti) loads landed; leave stage(ti+1)'s
    // LPS loads in flight. THEN barrier certifies all waves.
    if (ti + 1 < nt) {
      if constexpr (LPS == 2)      asm volatile("s_waitcnt vmcnt(2)" ::: "memory");
      else if constexpr (LPS == 3) asm volatile("s_waitcnt vmcnt(3)" ::: "memory");
      else                         asm volatile("s_waitcnt vmcnt(4)" ::: "memory");
    } else {
      asm volatile("s_waitcnt vmcnt(0)" ::: "memory");
    }
    __builtin_amdgcn_s_barrier();
    __builtin_amdgcn_sched_barrier(0);
    if (ti + 2 < nt) stage((ti + 2) << 5, lds + ps * BUFSZ);
    __builtin_amdgcn_s_setprio(1);
    compute(lds + cs * BUFSZ);
    __builtin_amdgcn_s_setprio(0);
    cs = (cs == 2) ? 0 : cs + 1;
    ps = (ps == 2) ? 0 : ps + 1;
  }

  // C/D layout: col = lane&15, row = (lane>>4)*4 + j  [m89-verified]
  const int cr = fh * 4;
  const float bscal = (bias_mode == 2) ? bias[0] : 0.f;
#pragma unroll
  for (int m = 0; m < MFR; ++m) {
#pragma unroll
    for (int n = 0; n < NFR; ++n) {
      const int col = tn + wc * WCC + n * 16 + fr;
      const float bv = (bias_mode == 1) ? bias[col] : bscal;
#pragma unroll
      for (int j = 0; j < 4; ++j) {
        const int row = tm + wr * WR + m * 16 + cr + j;
        float v = acc[m][n][j] + bv;
        if (relu) v = fmaxf(v, 0.f);
        if (out_bf16)
          ((ushort*)C)[(size_t)row * ldc + col] = f2bf(v);
        else
          ((float*)C)[(size_t)row * ldc + col] = v;
      }
    }
  }
}

// GEMM1 (t1 = relu(hs@W1^T + b1c), 8192x1024 K=1024, 128x128 tiles -> 512
// blocks) + MT rider (MT = bt(WbT, w2hT) [512x512] K=512, 16 blocks).
// grid (8, 66) = 528 blocks (%8==0).
__global__ __launch_bounds__(256)
void k_g1mt(const ushort* __restrict__ hs_bf, const ushort* __restrict__ W1,
            const float* __restrict__ b1c, ushort* __restrict__ t1,
            const ushort* __restrict__ WbT, const ushort* __restrict__ w2hT,
            ushort* __restrict__ MTb) {
  __shared__ ushort lds[3 * (128 + 128) * 32];  // 48 KB -> 3 blocks/CU
  const int flat = blockIdx.y * 8 + blockIdx.x;
  const int f2 = (flat & 7) * 66 + (flat >> 3);  // XCD-bijective swizzle
  const int by = f2 >> 3, bx = f2 & 7;
  if (by < 64) {
    gemm_body<128, 128>(hs_bf, W1, b1c, 1, t1, 1, 1,
                        HIDDEN, HIDDEN, 1024, HIDDEN, by * 128, bx * 128, lds);
  } else {
    const int idx = (by - 64) * 8 + bx;  // [0,16)
    gemm_body<128, 128>(WbT, w2hT, nullptr, 0, MTb, 1, 0,
                        AP, AP, AP, AP, (idx >> 2) * 128, (idx & 3) * 128, lds);
  }
}

// Generic batched GEMM: z-strided A/B/C (element strides), runtime flags.
template <int BM, int BN>
__global__ __launch_bounds__(256)
void k_gemm_rt(const ushort* __restrict__ A, const ushort* __restrict__ B,
               const float* __restrict__ bias, int bias_mode,
               void* __restrict__ C, int out_bf16, int relu,
               int lda, int ldb, int ldc, int K,
               long aBS, long bBS, long cBS) {
  __shared__ ushort lds[3 * (BM + BN) * 32];
  const int gx = gridDim.x, gy = gridDim.y;
  const int gxy = gx * gy;
  const int nwg = gxy * gridDim.z;
  const int flat = (blockIdx.z * gy + blockIdx.y) * gx + blockIdx.x;
  const int q = nwg >> 3;
  const int f2 = (flat & 7) * q + (flat >> 3);  // bijective: nwg % 8 == 0
  const int bz = f2 / gxy;
  const int rm = f2 - bz * gxy;
  const int by = rm / gx;
  const int bx = rm - by * gx;

  const ushort* Az = A + (size_t)aBS * bz;
  const ushort* Bz = B + (size_t)bBS * bz;
  void* Cz = out_bf16 ? (void*)((ushort*)C + (size_t)cBS * bz)
                      : (void*)((float*)C + (size_t)cBS * bz);
  gemm_body<BM, BN>(Az, Bz, bias, bias_mode, Cz, out_bf16, relu,
                    lda, ldb, ldc, K, by * BM, bx * BN, lds);
}

extern "C" void kernel_launch(void* const* d_in, const int* in_sizes, int n_in,
                              void* d_out, int out_size, void* d_ws, size_t ws_size,
                              hipStream_t stream) {
  const float* hs  = (const float*)d_in[0];
  const float* w1h = (const float*)d_in[1];
  const float* b1h = (const float*)d_in[2];
  const float* w2h = (const float*)d_in[3];
  const float* b2h = (const float*)d_in[4];
  const float* w1d = (const float*)d_in[5];
  const float* b1d = (const float*)d_in[6];
  const float* w2d = (const float*)d_in[7];
  const float* b2d = (const float*)d_in[8];
  const float* Wb  = (const float*)d_in[9];
  const float* bb  = (const float*)d_in[10];

  char* ws = (char*)d_ws;
  ushort* hs_bf = (ushort*)(ws + 0);          // 16 MB
  ushort* W1    = (ushort*)(ws + 16777216);   // 2 MB
  ushort* WbT   = (ushort*)(ws + 18874368);   // 512 KB
  ushort* w2hT  = (ushort*)(ws + 19398656);   // 512 KB
  ushort* MT    = (ushort*)(ws + 19922944);   // 512 KB
  ushort* W2    = (ushort*)(ws + 20447232);   // 512 KB (= MT + 512*512 elems!)
  ushort* t1    = (ushort*)(ws + 20971520);   // 16 MB
  ushort* hw    = (ushort*)(ws + 37748736);   // 16 MB (headW 8MB | dep 8MB)
  float*  b1c   = (float*)(ws + 54525952);    // 4 KB
  float*  out   = (float*)d_out;

  k_prep_all<<<7300, 256, 0, stream>>>(w1h, b1h, w1d, b1d, w2h, b2h, w2d, b2d,
                                       Wb, (const float4*)hs,
                                       W1, WbT, w2hT, W2, b1c, hs_bf);

  // GEMM1 + MT rider: 528 blocks
  k_g1mt<<<dim3(8, 66), 256, 0, stream>>>(hs_bf, W1, b1c, t1, WbT, w2hT, MT);

  // GEMM2: z=0 headW = t1[:,:512] @ MT^T ; z=1 dep = t1[:,512:] @ W2^T
  // 128x128 tiles: (4, 64, 2) = 512 blocks.
  k_gemm_rt<128, 128><<<dim3(4, 64, 2), 256, 0, stream>>>(
      t1, MT, nullptr, 0, hw, 1, 0, 1024, AP, AP, AP,
      /*aBS=*/AP, /*bBS=*/(long)AP * AP, /*cBS=*/(long)ROWS * AP);

  // GEMM3: scores_b = headW_b @ dep_b^T + bb -> f32 out.
  // 128x64 tiles: (8, 4, 16) = 512 blocks.
  k_gemm_rt<128, 64><<<dim3(8, 4, 16), 256, 0, stream>>>(
      hw, hw + (size_t)ROWS * AP, bb, 2, out, 0, 0, AP, AP, 512, AP,
      /*aBS=*/(long)512 * AP, /*bBS=*/(long)512 * AP, /*cBS=*/(long)512 * 512);
}